// Round 3
// baseline (445.452 us; speedup 1.0000x reference)
//
#include <hip/hip_runtime.h>
#include <math.h>

#define B_ 2
#define N_ 16384
#define V_ 10475
#define J_ 55
#define K_ 6

constexpr int SEG  = 4;     // V-segments (waves) per point-block
constexpr int T_   = 8;     // per-lane pool depth (coarse 32-bit keys)
constexpr int KBLK = SEG * 64;

// ---------------------------------------------------------------------------
// P0: pack verts as (x,y,z,v2) and points as (px,py,pz,p2) into ws (f32
// screen only — all final decisions re-done in f64)
// ---------------------------------------------------------------------------
__global__ void prep_kernel(const float* __restrict__ x,
                            const float* __restrict__ cam,
                            const float* __restrict__ pverts,
                            float4* __restrict__ pv,
                            float4* __restrict__ px) {
    int i = blockIdx.x * blockDim.x + threadIdx.x;
    const int nv = B_ * V_;
    if (i < nv) {
        float vx = pverts[i * 3 + 0];
        float vy = pverts[i * 3 + 1];
        float vz = pverts[i * 3 + 2];
        float v2 = vx * vx + vy * vy + vz * vz;
        pv[i] = make_float4(vx, vy, vz, v2);
    }
    int j = i - nv;
    if (j >= 0 && j < B_ * N_) {
        int b = j >> 14;
        float s  = cam[b * 3 + 0];
        float tx = cam[b * 3 + 1];
        float ty = cam[b * 3 + 2];
        float X = x[j * 3 + 0], Y = x[j * 3 + 1], Z = x[j * 3 + 2];
        float pxv = X / s - tx;
        float pyv = Y / s - ty;
        float pzv = Z / s;
        px[j] = make_float4(pxv, pyv, pzv, pxv * pxv + pyv * pyv + pzv * pzv);
    }
}

// ---------------------------------------------------------------------------
// K1: f32 screen with packed 32-bit keys (flip(d2)[31:14] | vert_idx[13:0]),
// branchless min/max bubble into an 8-deep per-lane pool; then f64 re-rank of
// the 4x8 candidate union with reference arithmetic (exact, stable ties).
// One wave per V-segment, 64 points per block, vert stream is wave-uniform
// (scalar loads, no LDS staging).
// ---------------------------------------------------------------------------
__global__ __launch_bounds__(KBLK) void knn_kernel(const float4* __restrict__ pv,
                                                   const float4* __restrict__ px,
                                                   const float* __restrict__ x,
                                                   const float* __restrict__ cam,
                                                   const float* __restrict__ pverts,
                                                   int* __restrict__ outI,
                                                   double* __restrict__ outD) {
    __shared__ unsigned int cK[SEG][64][T_];

    const int tid  = threadIdx.x;
    const int lane = tid & 63;
    const int wid  = __builtin_amdgcn_readfirstlane(tid >> 6);  // uniform
    const int bid  = blockIdx.x;
    const int b    = bid >> 8;                 // 256 point-blocks per batch
    const int n    = ((bid & 255) << 6) + lane;

    const float4 P = px[b * N_ + n];

    unsigned int bK[T_];
#pragma unroll
    for (int t = 0; t < T_; ++t) bK[t] = 0xFFFFFFFFu;
    unsigned int gate = 0xFFFFFFFFu;

    const int lo = (V_ * wid) / SEG;
    const int hi = (V_ * (wid + 1)) / SEG;
    const float4* vb = pv + b * V_;

#pragma unroll 4
    for (int i = lo; i < hi; ++i) {
        float4 q = vb[i];                       // wave-uniform -> scalar load
        float dot = fmaf(P.z, q.z, fmaf(P.y, q.y, P.x * q.x));
        float d2  = fmaf(-2.0f, dot, P.w + q.w);
        unsigned int ub = __float_as_uint(d2);
        // monotone float->uint flip (handles possible tiny negatives)
        unsigned int fl = ub ^ (0x80000000u | (unsigned int)(((int)ub) >> 31));
        unsigned int key = (fl & 0xFFFFC000u) | (unsigned int)i;  // V_ < 2^14
        if (key < gate) {                       // strict: stable vs idx order
#pragma unroll
            for (int t = 0; t < T_; ++t) {
                unsigned int mn = key < bK[t] ? key : bK[t];
                unsigned int mx = key < bK[t] ? bK[t] : key;
                bK[t] = mn;
                key = mx;
            }
            gate = bK[T_ - 1];
        }
    }

#pragma unroll
    for (int t = 0; t < T_; ++t) cK[wid][lane][t] = bK[t];
    __syncthreads();

    if (wid == 0) {
        // --- f64 re-rank of the 32-candidate pool, reference arithmetic ---
        const int gp = b * N_ + n;
        const double cs = (double)cam[b * 3 + 0];
        const double tx = (double)cam[b * 3 + 1];
        const double ty = (double)cam[b * 3 + 2];
        const double PX = (double)x[gp * 3 + 0] / cs - tx;
        const double PY = (double)x[gp * 3 + 1] / cs - ty;
        const double PZ = (double)x[gp * 3 + 2] / cs;
        const double P2 = PX * PX + PY * PY + PZ * PZ;

        double mD[K_];
        int    mI[K_];
#pragma unroll
        for (int k = 0; k < K_; ++k) { mD[k] = 1.0e300; mI[k] = 0x7fffffff; }

        for (int ss = 0; ss < SEG; ++ss) {
            for (int t = 0; t < T_; ++t) {
                int gi = (int)(cK[ss][lane][t] & 0x3FFFu);
                const float* vp = pverts + ((size_t)(b * V_ + gi)) * 3;
                double vx = (double)vp[0], vy = (double)vp[1], vz = (double)vp[2];
                double v2 = vx * vx + vy * vy + vz * vz;
                double dot = PX * vx + PY * vy + PZ * vz;
                double d = P2 + v2 - 2.0 * dot;     // reference expanded form
                bool ins = (d < mD[K_ - 1]) ||
                           (d == mD[K_ - 1] && gi < mI[K_ - 1]);
                if (ins) {
                    mD[K_ - 1] = d; mI[K_ - 1] = gi;
#pragma unroll
                    for (int k2 = K_ - 1; k2 > 0; --k2) {
                        bool sw = (mD[k2] < mD[k2 - 1]) ||
                                  (mD[k2] == mD[k2 - 1] && mI[k2] < mI[k2 - 1]);
                        if (sw) {
                            double td = mD[k2]; mD[k2] = mD[k2 - 1]; mD[k2 - 1] = td;
                            int    ti = mI[k2]; mI[k2] = mI[k2 - 1]; mI[k2 - 1] = ti;
                        }
                    }
                }
            }
        }
        const int base = gp * K_;
#pragma unroll
        for (int k = 0; k < K_; ++k) { outI[base + k] = mI[k]; outD[base + k] = mD[k]; }
    }
}

// ---------------------------------------------------------------------------
// K2: wave-per-point epilogue, all decision math in f64.
// lanes 0..54 carry the lbs row (coalesced); lanes 0..15 carry the 4x4
// transform blend; quad-reduce applies the transform.
// ---------------------------------------------------------------------------
__global__ __launch_bounds__(256) void epilogue_kernel(const float* __restrict__ lbs,
                                                       const float* __restrict__ vt,
                                                       const float* __restrict__ x,
                                                       const float* __restrict__ cam,
                                                       const int* __restrict__ knnI,
                                                       const double* __restrict__ knnD,
                                                       float* __restrict__ out) {
    const int lane = threadIdx.x & 63;
    const int w    = threadIdx.x >> 6;
    const int i    = blockIdx.x * 4 + w;       // point id; grid = B*N/4
    const int b    = i >> 14;

    const double cs = (double)cam[b * 3 + 0];
    const double tx = (double)cam[b * 3 + 1];
    const double ty = (double)cam[b * 3 + 2];
    const double PX = (double)x[i * 3 + 0] / cs - tx;
    const double PY = (double)x[i * 3 + 1] / cs - ty;
    const double PZ = (double)x[i * 3 + 2] / cs;

    int idx[K_];
    double d2[K_];
#pragma unroll
    for (int k = 0; k < K_; ++k) { idx[k] = knnI[i * K_ + k]; d2[k] = knnD[i * K_ + k]; }

    const double WSTD2 = 2.0 * (0.1 * 0.1);    // 0.020000000000000004
    // conf > 0.9  <=>  ssum < -WSTD2 * ln(0.9)   (exact algebraic transform)
    const double SS_THR = WSTD2 * 0.10536051565782630122750098083931;

    float v0 = (lane < J_) ? lbs[idx[0] * J_ + lane] : 0.0f;

    double wgt[K_];
    wgt[0] = exp(-fmax(d2[0], 0.0));           // conf(k=0) == 1 always
#pragma unroll
    for (int k = 1; k < K_; ++k) {
        float vk = (lane < J_) ? lbs[idx[k] * J_ + lane] : 0.0f;
        double s = fabs((double)vk - (double)v0);
#pragma unroll
        for (int m = 1; m < 64; m <<= 1) s += __shfl_xor(s, m, 64);
        double conf = (s < SS_THR) ? 1.0 : 0.0;
        wgt[k] = exp(-fmax(d2[k], 0.0)) * conf;
    }
    double wsum = 0.0;
#pragma unroll
    for (int k = 0; k < K_; ++k) wsum += wgt[k];

    // blend transforms: lane e < 16 accumulates element e of the 4x4
    double acc = 0.0;
    if (lane < 16) {
#pragma unroll
        for (int k = 0; k < K_; ++k) {
            double wk = wgt[k] / wsum;
            acc += wk * (double)vt[((size_t)(b * V_ + idx[k])) * 16 + lane];
        }
    }

    // apply: row r = lane>>2 (r<3), col c = lane&3; P = (PX,PY,PZ,1)
    const int c = lane & 3;
    double pc = (c == 0) ? PX : (c == 1) ? PY : (c == 2) ? PZ : 1.0;
    double part = acc * pc;
    part += __shfl_xor(part, 1, 64);
    part += __shfl_xor(part, 2, 64);
    if (lane == 0 || lane == 4 || lane == 8)
        out[i * 3 + (lane >> 2)] = (float)part;
}

// ---------------------------------------------------------------------------
extern "C" void kernel_launch(void* const* d_in, const int* in_sizes, int n_in,
                              void* d_out, int out_size, void* d_ws, size_t ws_size,
                              hipStream_t stream) {
    const float* x      = (const float*)d_in[0];  // [B,N,3]
    const float* cam    = (const float*)d_in[1];  // [B,3]
    const float* lbs    = (const float*)d_in[2];  // [V,J]
    const float* vt     = (const float*)d_in[3];  // [B,V,4,4]
    const float* pverts = (const float*)d_in[4];  // [B,V,3]
    float* out = (float*)d_out;                   // [B,N,3]

    char* ws = (char*)d_ws;
    float4* pv   = (float4*)ws;                                       // B*V float4
    float4* px   = (float4*)(ws + (size_t)B_ * V_ * 16);              // B*N float4
    int*    knnI = (int*)(ws + (size_t)B_ * V_ * 16 + (size_t)B_ * N_ * 16);
    double* knnD = (double*)((char*)knnI + (size_t)B_ * N_ * K_ * 4); // 8B aligned

    const int totalPrep = B_ * V_ + B_ * N_;
    prep_kernel<<<(totalPrep + 255) / 256, 256, 0, stream>>>(x, cam, pverts, pv, px);
    knn_kernel<<<B_ * (N_ / 64), KBLK, 0, stream>>>(pv, px, x, cam, pverts, knnI, knnD);
    epilogue_kernel<<<(B_ * N_) / (256 / 64), 256, 0, stream>>>(lbs, vt, x, cam, knnI, knnD, out);
}

// Round 4
// 260.890 us; speedup vs baseline: 1.7074x; 1.7074x over previous
//
#include <hip/hip_runtime.h>
#include <math.h>

#define B_ 2
#define N_ 16384
#define V_ 10475
#define J_ 55
#define K_ 6

constexpr int SEG  = 16;    // V-segments (waves) per point-block
constexpr int T_   = 6;     // per-lane pool depth (safe: <=6 of top-6 per segment)
constexpr int TILE = 2048;  // verts staged in LDS per tile
constexpr int KBLK = SEG * 64;  // 1024 threads

// ---------------------------------------------------------------------------
// P0: pack verts as (x,y,z,v2) and points as (px,py,pz,p2) into ws (f32
// screen only — all final decisions re-done in f64)
// ---------------------------------------------------------------------------
__global__ void prep_kernel(const float* __restrict__ x,
                            const float* __restrict__ cam,
                            const float* __restrict__ pverts,
                            float4* __restrict__ pv,
                            float4* __restrict__ px) {
    int i = blockIdx.x * blockDim.x + threadIdx.x;
    const int nv = B_ * V_;
    if (i < nv) {
        float vx = pverts[i * 3 + 0];
        float vy = pverts[i * 3 + 1];
        float vz = pverts[i * 3 + 2];
        pv[i] = make_float4(vx, vy, vz, vx * vx + vy * vy + vz * vz);
    }
    int j = i - nv;
    if (j >= 0 && j < B_ * N_) {
        int b = j >> 14;
        float s  = cam[b * 3 + 0];
        float tx = cam[b * 3 + 1];
        float ty = cam[b * 3 + 2];
        float pxv = x[j * 3 + 0] / s - tx;
        float pyv = x[j * 3 + 1] / s - ty;
        float pzv = x[j * 3 + 2] / s;
        px[j] = make_float4(pxv, pyv, pzv, pxv * pxv + pyv * pyv + pzv * pzv);
    }
}

// ---------------------------------------------------------------------------
// K1: f32 screen. 64 points per block (one per lane), 16 waves each scan a
// disjoint 1/16 slice of each LDS vert tile (broadcast reads). Per-lane pool
// of 6 packed keys ((d2+bias)[31:14] | idx[13:0]) maintained branchlessly
// with a min/max bubble (2 VALU per level). Then wave 0 re-ranks the
// 16x6 = 96 candidate union in f64 with the reference's exact expanded
// formula and stable (d2, idx) tie ordering.
// ---------------------------------------------------------------------------
__global__ __launch_bounds__(KBLK, 8) void knn_kernel(const float4* __restrict__ pv,
                                                      const float4* __restrict__ px,
                                                      const float* __restrict__ x,
                                                      const float* __restrict__ cam,
                                                      const float* __restrict__ pverts,
                                                      int* __restrict__ outI,
                                                      double* __restrict__ outD) {
    __shared__ float4 tile[TILE];
    __shared__ unsigned int cK[SEG][64][T_];

    const int tid  = threadIdx.x;
    const int lane = tid & 63;
    const int wid  = tid >> 6;
    const int bid  = blockIdx.x;
    const int b    = bid >> 8;                 // 256 point-blocks per batch
    const int n    = ((bid & 255) << 6) + lane;

    const float4 P = px[b * N_ + n];
    // d2 + bias = fma(-2Px,qx, fma(-2Py,qy, fma(-2Pz,qz, (P2+bias) + v2)))
    // bias 1e-4 > worst-case f32 cancellation error (~2e-5) => always > 0,
    // and x -> x+bias is order-preserving, so uint compare on the raw bits
    // is a valid distance order. f64 re-rank fixes any truncation ties.
    const float Ax = -2.0f * P.x, Ay = -2.0f * P.y, Az = -2.0f * P.z;
    const float C  = P.w + 1.0e-4f;

    unsigned int bK[T_];
#pragma unroll
    for (int t = 0; t < T_; ++t) bK[t] = 0xFFFFFFFFu;

    const float4* vb = pv + b * V_;
    for (int t0 = 0; t0 < V_; t0 += TILE) {
        const int cnt = min(TILE, V_ - t0);
        for (int i = tid; i < cnt; i += KBLK) tile[i] = vb[t0 + i];
        __syncthreads();

        const int lo = wid * (TILE / SEG);
        const int hi = min(lo + (TILE / SEG), cnt);
#pragma unroll 2
        for (int i = lo; i < hi; ++i) {
            float4 q = tile[i];              // same addr all lanes: broadcast
            float d2 = fmaf(Ax, q.x, fmaf(Ay, q.y, fmaf(Az, q.z, C + q.w)));
            unsigned int key = (__float_as_uint(d2) & 0xFFFFC000u)
                             | (unsigned int)(t0 + i);        // V_ < 2^14
#pragma unroll
            for (int t = 0; t < T_; ++t) {   // branchless sorted-pool bubble
                unsigned int mn = key < bK[t] ? key : bK[t];
                unsigned int mx = key < bK[t] ? bK[t] : key;
                bK[t] = mn;
                key   = mx;
            }
        }
        __syncthreads();
    }

#pragma unroll
    for (int t = 0; t < T_; ++t) cK[wid][lane][t] = bK[t];
    __syncthreads();

    if (wid == 0) {
        // --- f64 re-rank of the 96-candidate pool, reference arithmetic ---
        const int gp = b * N_ + n;
        const double cs = (double)cam[b * 3 + 0];
        const double tx = (double)cam[b * 3 + 1];
        const double ty = (double)cam[b * 3 + 2];
        const double PX = (double)x[gp * 3 + 0] / cs - tx;
        const double PY = (double)x[gp * 3 + 1] / cs - ty;
        const double PZ = (double)x[gp * 3 + 2] / cs;
        const double P2 = PX * PX + PY * PY + PZ * PZ;

        double mD[K_];
        int    mI[K_];
#pragma unroll
        for (int k = 0; k < K_; ++k) { mD[k] = 1.0e300; mI[k] = 0x7fffffff; }

        for (int ss = 0; ss < SEG; ++ss) {
            for (int t = 0; t < T_; ++t) {
                int gi = (int)(cK[ss][lane][t] & 0x3FFFu);
                if (gi >= V_) continue;      // never taken (all slots valid)
                const float* vp = pverts + ((size_t)(b * V_ + gi)) * 3;
                double vx = (double)vp[0], vy = (double)vp[1], vz = (double)vp[2];
                double v2 = vx * vx + vy * vy + vz * vz;
                double dot = PX * vx + PY * vy + PZ * vz;
                double d = P2 + v2 - 2.0 * dot;     // reference expanded form
                bool ins = (d < mD[K_ - 1]) ||
                           (d == mD[K_ - 1] && gi < mI[K_ - 1]);
                if (ins) {
                    mD[K_ - 1] = d; mI[K_ - 1] = gi;
#pragma unroll
                    for (int k2 = K_ - 1; k2 > 0; --k2) {
                        bool sw = (mD[k2] < mD[k2 - 1]) ||
                                  (mD[k2] == mD[k2 - 1] && mI[k2] < mI[k2 - 1]);
                        if (sw) {
                            double td = mD[k2]; mD[k2] = mD[k2 - 1]; mD[k2 - 1] = td;
                            int    ti = mI[k2]; mI[k2] = mI[k2 - 1]; mI[k2 - 1] = ti;
                        }
                    }
                }
            }
        }
        const int base = gp * K_;
#pragma unroll
        for (int k = 0; k < K_; ++k) { outI[base + k] = mI[k]; outD[base + k] = mD[k]; }
    }
}

// ---------------------------------------------------------------------------
// K2: thread = (point, k). conf decision + w_k = exp(-d2)*conf in f64.
// Writes w IN PLACE over knnD (thread (p,k) owns slot p*6+k; knnD[p*6+0] is
// only read by thread (p,0); knnI is untouched) — keeps ws footprint small.
// ---------------------------------------------------------------------------
__global__ __launch_bounds__(256) void weight_kernel(const float* __restrict__ lbs,
                                                     const int* __restrict__ knnI,
                                                     double* __restrict__ knnD) {
    int gid = blockIdx.x * blockDim.x + threadIdx.x;
    if (gid >= B_ * N_ * K_) return;
    int p = gid / K_;
    int k = gid - p * K_;
    int base = p * K_;

    double d2 = knnD[base + k];
    double w = exp(-fmax(d2, 0.0));
    if (k > 0) {
        const double WSTD2 = 2.0 * (0.1 * 0.1);   // 0.020000000000000004
        // conf > 0.9  <=>  ssum < -WSTD2*ln(0.9)  (exact algebraic transform)
        const double SS_THR = WSTD2 * 0.10536051565782630122750098083931;
        int i0 = knnI[base];
        int ik = knnI[base + k];
        const float* r0 = lbs + (size_t)i0 * J_;
        const float* rk = lbs + (size_t)ik * J_;
        double s0 = 0.0, s1 = 0.0, s2 = 0.0, s3 = 0.0;
        int j = 0;
        for (; j + 3 < J_; j += 4) {
            s0 += fabs((double)rk[j]     - (double)r0[j]);
            s1 += fabs((double)rk[j + 1] - (double)r0[j + 1]);
            s2 += fabs((double)rk[j + 2] - (double)r0[j + 2]);
            s3 += fabs((double)rk[j + 3] - (double)r0[j + 3]);
        }
        for (; j < J_; ++j) s0 += fabs((double)rk[j] - (double)r0[j]);
        double ssum = (s0 + s1) + (s2 + s3);
        if (!(ssum < SS_THR)) w = 0.0;
    }
    knnD[base + k] = w;
}

// ---------------------------------------------------------------------------
// K3: thread = point. normalize weights, blend transforms (float4 gathers,
// 64B-aligned rows), apply to posed point, write out. All f64.
// ---------------------------------------------------------------------------
__global__ __launch_bounds__(256) void blend_kernel(const float* __restrict__ vt,
                                                    const float* __restrict__ x,
                                                    const float* __restrict__ cam,
                                                    const int* __restrict__ knnI,
                                                    const double* __restrict__ wbuf,
                                                    float* __restrict__ out) {
    int i = blockIdx.x * blockDim.x + threadIdx.x;
    if (i >= B_ * N_) return;
    const int b = i >> 14;

    const double cs = (double)cam[b * 3 + 0];
    const double tx = (double)cam[b * 3 + 1];
    const double ty = (double)cam[b * 3 + 2];
    const double PX = (double)x[i * 3 + 0] / cs - tx;
    const double PY = (double)x[i * 3 + 1] / cs - ty;
    const double PZ = (double)x[i * 3 + 2] / cs;

    int idx[K_];
    double w[K_];
    double wsum = 0.0;
#pragma unroll
    for (int k = 0; k < K_; ++k) {
        idx[k] = knnI[i * K_ + k];
        w[k] = wbuf[i * K_ + k];
        wsum += w[k];
    }

    double acc[12];
#pragma unroll
    for (int r = 0; r < 12; ++r) acc[r] = 0.0;
#pragma unroll
    for (int k = 0; k < K_; ++k) {
        double wk = w[k] / wsum;
        const float4* T = (const float4*)(vt + ((size_t)(b * V_ + idx[k])) * 16);
#pragma unroll
        for (int r = 0; r < 3; ++r) {
            float4 row = T[r];
            acc[r * 4 + 0] += wk * (double)row.x;
            acc[r * 4 + 1] += wk * (double)row.y;
            acc[r * 4 + 2] += wk * (double)row.z;
            acc[r * 4 + 3] += wk * (double)row.w;
        }
    }
    out[i * 3 + 0] = (float)(acc[0] * PX + acc[1] * PY + acc[2]  * PZ + acc[3]);
    out[i * 3 + 1] = (float)(acc[4] * PX + acc[5] * PY + acc[6]  * PZ + acc[7]);
    out[i * 3 + 2] = (float)(acc[8] * PX + acc[9] * PY + acc[10] * PZ + acc[11]);
}

// ---------------------------------------------------------------------------
extern "C" void kernel_launch(void* const* d_in, const int* in_sizes, int n_in,
                              void* d_out, int out_size, void* d_ws, size_t ws_size,
                              hipStream_t stream) {
    const float* x      = (const float*)d_in[0];  // [B,N,3]
    const float* cam    = (const float*)d_in[1];  // [B,3]
    const float* lbs    = (const float*)d_in[2];  // [V,J]
    const float* vt     = (const float*)d_in[3];  // [B,V,4,4]
    const float* pverts = (const float*)d_in[4];  // [B,V,3]
    float* out = (float*)d_out;                   // [B,N,3]

    char* ws = (char*)d_ws;
    float4* pv   = (float4*)ws;                                       // B*V float4
    float4* px   = (float4*)(ws + (size_t)B_ * V_ * 16);              // B*N float4
    int*    knnI = (int*)(ws + (size_t)B_ * V_ * 16 + (size_t)B_ * N_ * 16);
    double* knnD = (double*)((char*)knnI + (size_t)B_ * N_ * K_ * 4); // 8B aligned

    const int totalPrep = B_ * V_ + B_ * N_;
    prep_kernel<<<(totalPrep + 255) / 256, 256, 0, stream>>>(x, cam, pverts, pv, px);
    knn_kernel<<<B_ * (N_ / 64), KBLK, 0, stream>>>(pv, px, x, cam, pverts, knnI, knnD);
    weight_kernel<<<(B_ * N_ * K_ + 255) / 256, 256, 0, stream>>>(lbs, knnI, knnD);
    blend_kernel<<<(B_ * N_ + 255) / 256, 256, 0, stream>>>(vt, x, cam, knnI, knnD, out);
}